// Round 2
// baseline (2119.870 us; speedup 1.0000x reference)
//
#include <hip/hip_runtime.h>
#include <hip/hip_bf16.h>

#define N_TOK 32768
#define DIM   256
#define KCB   8192

// ---------------------------------------------------------------------------
// Kernel 0: transpose w_out [D][D] -> wT[j][d] so codebook build reads coalesced
// ---------------------------------------------------------------------------
__global__ __launch_bounds__(256) void transpose_w(const float* __restrict__ w,
                                                   float* __restrict__ wT) {
    __shared__ float tile[32][33];
    int bx = blockIdx.x & 7, by = blockIdx.x >> 3;
    int x0 = bx * 32, y0 = by * 32;
    int tx = threadIdx.x & 31, ty = threadIdx.x >> 5;
    #pragma unroll
    for (int i = 0; i < 32; i += 8)
        tile[ty + i][tx] = w[(y0 + ty + i) * DIM + x0 + tx];
    __syncthreads();
    #pragma unroll
    for (int i = 0; i < 32; i += 8)
        wT[(x0 + ty + i) * DIM + y0 + tx] = tile[tx][ty + i];
}

// ---------------------------------------------------------------------------
// Kernel 1: codebook[k][d] = sum_j emb[k][j] * w_out[d][j]
// Sequential-j fp32 FMA chain per element == OpenBLAS sgemm micro-kernel order.
// ---------------------------------------------------------------------------
#define KPB 8
__global__ __launch_bounds__(256) void build_codebook(const float* __restrict__ emb,
                                                      const float* __restrict__ wT,
                                                      float* __restrict__ cb) {
    __shared__ float e[KPB][DIM];
    const int k0 = blockIdx.x * KPB;
    const int t = threadIdx.x;
    for (int i = t; i < KPB * DIM / 4; i += 256)
        ((float4*)&e[0][0])[i] = ((const float4*)(emb + (size_t)k0 * DIM))[i];
    __syncthreads();
    const int d = t;
    float acc[KPB];
    #pragma unroll
    for (int kk = 0; kk < KPB; ++kk) acc[kk] = 0.f;
    for (int j = 0; j < DIM; ++j) {               // ascending j, single FMA chain
        float w = wT[j * DIM + d];
        #pragma unroll
        for (int kk = 0; kk < KPB; ++kk)
            acc[kk] = fmaf(e[kk][j], w, acc[kk]);
    }
    #pragma unroll
    for (int kk = 0; kk < KPB; ++kk)
        cb[(size_t)(k0 + kk) * DIM + d] = acc[kk];
}

// ---------------------------------------------------------------------------
// numpy pairwise_sum emulation (fp32, n=256 = 128+128, 8-accumulator blocks).
// Products rounded to fp32 BEFORE summation (numpy materializes a*a temp).
// ---------------------------------------------------------------------------
__device__ __forceinline__ float np_sumsq_256(const float* __restrict__ a) {
    #pragma clang fp contract(off)
    float halves[2];
    for (int h = 0; h < 2; ++h) {
        const float* b = a + h * 128;
        float r0, r1, r2, r3, r4, r5, r6, r7;
        {
            float v0=b[0], v1=b[1], v2=b[2], v3=b[3], v4=b[4], v5=b[5], v6=b[6], v7=b[7];
            r0=v0*v0; r1=v1*v1; r2=v2*v2; r3=v3*v3; r4=v4*v4; r5=v5*v5; r6=v6*v6; r7=v7*v7;
        }
        for (int i = 8; i < 128; i += 8) {
            float v0=b[i+0], v1=b[i+1], v2=b[i+2], v3=b[i+3],
                  v4=b[i+4], v5=b[i+5], v6=b[i+6], v7=b[i+7];
            r0 = r0 + v0*v0; r1 = r1 + v1*v1; r2 = r2 + v2*v2; r3 = r3 + v3*v3;
            r4 = r4 + v4*v4; r5 = r5 + v5*v5; r6 = r6 + v6*v6; r7 = r7 + v7*v7;
        }
        halves[h] = ((r0 + r1) + (r2 + r3)) + ((r4 + r5) + (r6 + r7));
    }
    return halves[0] + halves[1];
}

__global__ __launch_bounds__(256) void x2_np(const float* __restrict__ x,
                                             float* __restrict__ x2) {
    int r = blockIdx.x * 256 + threadIdx.x;      // 128 blocks
    x2[r] = np_sumsq_256(x + (size_t)r * DIM);
}

__global__ __launch_bounds__(256) void c2_np(const float* __restrict__ cb,
                                             float* __restrict__ c2) {
    int k = blockIdx.x * 256 + threadIdx.x;      // 32 blocks
    c2[k] = np_sumsq_256(cb + (size_t)k * DIM);
}

// ---------------------------------------------------------------------------
// Kernel 2: fused GEMM + fp32-exact dist + row argmin (first-index ties).
// xc accumulated as sequential-k fp32 FMA chain (== BLAS order).
// d = fl(fl(x2 - fl(2*xc)) + c2), packed (mono(d)<<32 | id), u64 atomicMin.
// ---------------------------------------------------------------------------
__global__ __launch_bounds__(256) void score_argmin(const float* __restrict__ x,
                                                    const float* __restrict__ cb,
                                                    const float* __restrict__ c2,
                                                    const float* __restrict__ x2,
                                                    unsigned long long* __restrict__ best) {
    #pragma clang fp contract(off)
    __shared__ float As[8][128];
    __shared__ float Bs[8][128];
    __shared__ unsigned long long red[128][16];

    const int row0 = blockIdx.x * 128;
    const int col0 = blockIdx.y * 128;
    const int t = threadIdx.x;
    const int tn = t & 15, tm = t >> 4;
    const int lrow = t >> 1, lseg = (t & 1) * 4;

    float acc[8][8];
    #pragma unroll
    for (int i = 0; i < 8; ++i)
        #pragma unroll
        for (int j = 0; j < 8; ++j) acc[i][j] = 0.f;

    const float* xp = x  + (size_t)(row0 + lrow) * DIM + lseg;
    const float* cp = cb + (size_t)(col0 + lrow) * DIM + lseg;

    for (int k0 = 0; k0 < DIM; k0 += 8) {
        float4 av = *(const float4*)(xp + k0);
        float4 bv = *(const float4*)(cp + k0);
        __syncthreads();
        As[lseg + 0][lrow] = av.x; As[lseg + 1][lrow] = av.y;
        As[lseg + 2][lrow] = av.z; As[lseg + 3][lrow] = av.w;
        Bs[lseg + 0][lrow] = bv.x; Bs[lseg + 1][lrow] = bv.y;
        Bs[lseg + 2][lrow] = bv.z; Bs[lseg + 3][lrow] = bv.w;
        __syncthreads();
        #pragma unroll
        for (int kk = 0; kk < 8; ++kk) {          // ascending k, single FMA chain
            float a[8], b[8];
            *(float4*)(a)     = *(const float4*)&As[kk][tm * 8];
            *(float4*)(a + 4) = *(const float4*)&As[kk][tm * 8 + 4];
            *(float4*)(b)     = *(const float4*)&Bs[kk][tn * 8];
            *(float4*)(b + 4) = *(const float4*)&Bs[kk][tn * 8 + 4];
            #pragma unroll
            for (int i = 0; i < 8; ++i)
                #pragma unroll
                for (int j = 0; j < 8; ++j)
                    acc[i][j] = fmaf(a[i], b[j], acc[i][j]);
        }
    }

    float c2v[8], x2v[8];
    #pragma unroll
    for (int j = 0; j < 8; ++j) c2v[j] = c2[col0 + tn * 8 + j];
    #pragma unroll
    for (int i = 0; i < 8; ++i) x2v[i] = x2[row0 + tm * 8 + i];

    #pragma unroll
    for (int i = 0; i < 8; ++i) {
        unsigned long long bp = ~0ull;
        #pragma unroll
        for (int j = 0; j < 8; ++j) {
            float tt = 2.0f * acc[i][j];          // exact
            float u  = x2v[i] - tt;               // fp32 round at ~256 (the bucket)
            float dd = u + c2v[j];                // fp32 round
            unsigned int ub = __float_as_uint(dd);
            ub = (ub >> 31) ? ~ub : (ub | 0x80000000u);   // monotonic map
            unsigned long long pk =
                ((unsigned long long)ub << 32) | (unsigned int)(col0 + tn * 8 + j);
            if (pk < bp) bp = pk;                 // min d, tie -> min id
        }
        red[tm * 8 + i][tn] = bp;
    }
    __syncthreads();
    if (t < 128) {
        unsigned long long m = red[t][0];
        #pragma unroll
        for (int j = 1; j < 16; ++j) {
            unsigned long long v = red[t][j];
            if (v < m) m = v;
        }
        atomicMin(&best[row0 + t], m);
    }
}

// ---------------------------------------------------------------------------
// Kernel 3: gather q = cb[id], write quantized + ids(float), accumulate loss.
// ---------------------------------------------------------------------------
__global__ __launch_bounds__(256) void finalize(const float* __restrict__ x,
                                                const float* __restrict__ cb,
                                                const unsigned long long* __restrict__ best,
                                                float* __restrict__ out,
                                                float* __restrict__ loss_acc) {
    const int r = blockIdx.x;
    const int d = threadIdx.x;
    const int id = (int)(best[r] & 0xFFFFFFFFu);
    const float q  = cb[(size_t)id * DIM + d];
    const float xv = x[(size_t)r * DIM + d];
    out[(size_t)r * DIM + d] = q;
    float df = xv - q;
    float v = df * df;
    #pragma unroll
    for (int o = 32; o > 0; o >>= 1) v += __shfl_down(v, o, 64);
    __shared__ float w4[4];
    if ((d & 63) == 0) w4[d >> 6] = v;
    __syncthreads();
    if (d == 0) {
        atomicAdd(loss_acc, w4[0] + w4[1] + w4[2] + w4[3]);
        out[(size_t)N_TOK * DIM + r] = (float)id;
    }
}

__global__ void write_loss(const float* __restrict__ loss_acc, float* __restrict__ out) {
    out[(size_t)N_TOK * DIM + N_TOK] =
        loss_acc[0] * (1.25f / ((float)N_TOK * (float)DIM));
}

// ---------------------------------------------------------------------------
extern "C" void kernel_launch(void* const* d_in, const int* in_sizes, int n_in,
                              void* d_out, int out_size, void* d_ws, size_t ws_size,
                              hipStream_t stream) {
    const float* x     = (const float*)d_in[0];
    const float* emb   = (const float*)d_in[1];
    const float* w_out = (const float*)d_in[2];
    float* out = (float*)d_out;

    char* ws = (char*)d_ws;
    unsigned long long* best = (unsigned long long*)ws;          // 262144 B
    float* loss_acc = (float*)(ws + 262144);                     // -> 262400
    float* x2 = (float*)(ws + 262400);                           // 131072 -> 393472
    float* wT = (float*)(ws + 393472);                           // 262144 -> 655616
    float* cb = (float*)(ws + 655616);                           // 8388608 -> 9044224
    float* c2 = (float*)(ws + 9044224);                          // 32768  -> 9076992

    hipMemsetAsync(best, 0xFF, 262144, stream);   // argmin table: +inf packed
    hipMemsetAsync(loss_acc, 0, 4, stream);

    transpose_w   <<<64,  256, 0, stream>>>(w_out, wT);
    build_codebook<<<KCB / KPB, 256, 0, stream>>>(emb, wT, cb);
    x2_np         <<<N_TOK / 256, 256, 0, stream>>>(x, x2);
    c2_np         <<<KCB / 256, 256, 0, stream>>>(cb, c2);
    score_argmin  <<<dim3(N_TOK / 128, KCB / 128), 256, 0, stream>>>(x, cb, c2, x2, best);
    finalize      <<<N_TOK, 256, 0, stream>>>(x, cb, best, out, loss_acc);
    write_loss    <<<1, 1, 0, stream>>>(loss_acc, out);
}

// Round 3
// 2116.577 us; speedup vs baseline: 1.0016x; 1.0016x over previous
//
#include <hip/hip_runtime.h>
#include <hip/hip_bf16.h>

#define N_TOK 32768
#define DIM   256
#define KCB   8192

// ---------------------------------------------------------------------------
// Kernel 0: transpose w_out [D][D] -> wT[j][d]
// ---------------------------------------------------------------------------
__global__ __launch_bounds__(256) void transpose_w(const float* __restrict__ w,
                                                   float* __restrict__ wT) {
    __shared__ float tile[32][33];
    int bx = blockIdx.x & 7, by = blockIdx.x >> 3;
    int x0 = bx * 32, y0 = by * 32;
    int tx = threadIdx.x & 31, ty = threadIdx.x >> 5;
    #pragma unroll
    for (int i = 0; i < 32; i += 8)
        tile[ty + i][tx] = w[(y0 + ty + i) * DIM + x0 + tx];
    __syncthreads();
    #pragma unroll
    for (int i = 0; i < 32; i += 8)
        wT[(x0 + ty + i) * DIM + y0 + tx] = tile[tx][ty + i];
}

// ---------------------------------------------------------------------------
// Kernel 1: codebook[k][d] = sum_j emb[k][j]*w_out[d][j], sequential-j FMA chain
// ---------------------------------------------------------------------------
#define KPB 8
__global__ __launch_bounds__(256) void build_codebook(const float* __restrict__ emb,
                                                      const float* __restrict__ wT,
                                                      float* __restrict__ cb) {
    __shared__ float e[KPB][DIM];
    const int k0 = blockIdx.x * KPB;
    const int t = threadIdx.x;
    for (int i = t; i < KPB * DIM / 4; i += 256)
        ((float4*)&e[0][0])[i] = ((const float4*)(emb + (size_t)k0 * DIM))[i];
    __syncthreads();
    const int d = t;
    float acc[KPB];
    #pragma unroll
    for (int kk = 0; kk < KPB; ++kk) acc[kk] = 0.f;
    for (int j = 0; j < DIM; ++j) {
        float w = wT[j * DIM + d];
        #pragma unroll
        for (int kk = 0; kk < KPB; ++kk)
            acc[kk] = fmaf(e[kk][j], w, acc[kk]);
    }
    #pragma unroll
    for (int kk = 0; kk < KPB; ++kk)
        cb[(size_t)(k0 + kk) * DIM + d] = acc[kk];
}

// ---------------------------------------------------------------------------
// numpy pairwise sum-of-squares, 2 threads/row (one per 128-half), float4 loads.
// Element-order identical to np: 8 accumulators mod-8, ascending i, tree combine.
// ---------------------------------------------------------------------------
__device__ __forceinline__ float np_sumsq_128(const float* __restrict__ b) {
    #pragma clang fp contract(off)
    float r0, r1, r2, r3, r4, r5, r6, r7;
    {
        float4 p = *(const float4*)(b);
        float4 q = *(const float4*)(b + 4);
        r0 = p.x * p.x; r1 = p.y * p.y; r2 = p.z * p.z; r3 = p.w * p.w;
        r4 = q.x * q.x; r5 = q.y * q.y; r6 = q.z * q.z; r7 = q.w * q.w;
    }
    #pragma unroll
    for (int i = 8; i < 128; i += 8) {
        float4 p = *(const float4*)(b + i);
        float4 q = *(const float4*)(b + i + 4);
        r0 = r0 + p.x * p.x; r1 = r1 + p.y * p.y;
        r2 = r2 + p.z * p.z; r3 = r3 + p.w * p.w;
        r4 = r4 + q.x * q.x; r5 = r5 + q.y * q.y;
        r6 = r6 + q.z * q.z; r7 = r7 + q.w * q.w;
    }
    return ((r0 + r1) + (r2 + r3)) + ((r4 + r5) + (r6 + r7));
}

__global__ __launch_bounds__(256) void sumsq_np(const float* __restrict__ a,
                                                float* __restrict__ out) {
    #pragma clang fp contract(off)
    int idx = blockIdx.x * 256 + threadIdx.x;
    int r = idx >> 1, h = idx & 1;
    float half = np_sumsq_128(a + (size_t)r * DIM + h * 128);
    float other = __shfl_xor(half, 1, 64);
    if (h == 0) out[r] = half + other;   // halves[0] + halves[1], np order
}

// ---------------------------------------------------------------------------
// Kernel 2: fused GEMM + fp32-exact dist + row argmin (first-index ties).
// 128x128 tile, BK=16, 256 thr, 8x8 micro-tile split 4+4 (conflict-free b128).
// ---------------------------------------------------------------------------
__device__ __forceinline__ unsigned long long shfl_xor_u64(unsigned long long v, int m) {
    unsigned int lo = (unsigned int)v, hi = (unsigned int)(v >> 32);
    lo = __shfl_xor(lo, m, 64);
    hi = __shfl_xor(hi, m, 64);
    return ((unsigned long long)hi << 32) | lo;
}

__global__ __launch_bounds__(256, 4) void score_argmin(const float* __restrict__ x,
                                                       const float* __restrict__ cb,
                                                       const float* __restrict__ c2,
                                                       const float* __restrict__ x2,
                                                       unsigned long long* __restrict__ best) {
    #pragma clang fp contract(off)
    __shared__ float As[16][128];
    __shared__ float Bs[16][128];

    const int row0 = blockIdx.x * 128;
    const int col0 = blockIdx.y * 128;
    const int t = threadIdx.x;
    const int tn = t & 15, tm = t >> 4;
    const int lrow = t >> 1, lseg = (t & 1) * 4;

    float acc[8][8];
    #pragma unroll
    for (int i = 0; i < 8; ++i)
        #pragma unroll
        for (int j = 0; j < 8; ++j) acc[i][j] = 0.f;

    const float* xp = x  + (size_t)(row0 + lrow) * DIM + lseg;
    const float* cp = cb + (size_t)(col0 + lrow) * DIM + lseg;

    for (int k0 = 0; k0 < DIM; k0 += 16) {
        float4 a0 = *(const float4*)(xp + k0);
        float4 a1 = *(const float4*)(xp + k0 + 8);
        float4 b0 = *(const float4*)(cp + k0);
        float4 b1 = *(const float4*)(cp + k0 + 8);
        __syncthreads();
        As[lseg + 0][lrow] = a0.x; As[lseg + 1][lrow] = a0.y;
        As[lseg + 2][lrow] = a0.z; As[lseg + 3][lrow] = a0.w;
        As[8 + lseg + 0][lrow] = a1.x; As[8 + lseg + 1][lrow] = a1.y;
        As[8 + lseg + 2][lrow] = a1.z; As[8 + lseg + 3][lrow] = a1.w;
        Bs[lseg + 0][lrow] = b0.x; Bs[lseg + 1][lrow] = b0.y;
        Bs[lseg + 2][lrow] = b0.z; Bs[lseg + 3][lrow] = b0.w;
        Bs[8 + lseg + 0][lrow] = b1.x; Bs[8 + lseg + 1][lrow] = b1.y;
        Bs[8 + lseg + 2][lrow] = b1.z; Bs[8 + lseg + 3][lrow] = b1.w;
        __syncthreads();
        #pragma unroll
        for (int kk = 0; kk < 16; ++kk) {   // ascending k: exact BLAS FMA chain
            float a[8], b[8];
            *(float4*)(a)     = *(const float4*)&As[kk][tm * 4];
            *(float4*)(a + 4) = *(const float4*)&As[kk][64 + tm * 4];
            *(float4*)(b)     = *(const float4*)&Bs[kk][tn * 4];
            *(float4*)(b + 4) = *(const float4*)&Bs[kk][64 + tn * 4];
            #pragma unroll
            for (int i = 0; i < 8; ++i)
                #pragma unroll
                for (int j = 0; j < 8; ++j)
                    acc[i][j] = fmaf(a[i], b[j], acc[i][j]);
        }
    }

    float c2v[8], x2v[8];
    #pragma unroll
    for (int j = 0; j < 4; ++j) {
        c2v[j]     = c2[col0 + tn * 4 + j];
        c2v[4 + j] = c2[col0 + 64 + tn * 4 + j];
    }
    #pragma unroll
    for (int i = 0; i < 4; ++i) {
        x2v[i]     = x2[row0 + tm * 4 + i];
        x2v[4 + i] = x2[row0 + 64 + tm * 4 + i];
    }

    #pragma unroll
    for (int i = 0; i < 8; ++i) {
        unsigned long long bp = ~0ull;
        #pragma unroll
        for (int j = 0; j < 8; ++j) {
            float tt = 2.0f * acc[i][j];     // exact (scale by 2)
            float u  = x2v[i] - tt;          // fp32 round @ ~256 (tie bucket)
            float dd = u + c2v[j];           // fp32 round
            unsigned int ub = __float_as_uint(dd);
            ub = (ub >> 31) ? ~ub : (ub | 0x80000000u);
            int id = col0 + ((j < 4) ? (tn * 4 + j) : (64 + tn * 4 + (j - 4)));
            unsigned long long pk = ((unsigned long long)ub << 32) | (unsigned int)id;
            if (pk < bp) bp = pk;            // min dist, tie -> min id
        }
        #pragma unroll
        for (int m = 1; m < 16; m <<= 1) {   // butterfly over tn (16 lanes)
            unsigned long long v = shfl_xor_u64(bp, m);
            if (v < bp) bp = v;
        }
        if (tn == 0) {
            int gr = row0 + ((i < 4) ? (tm * 4 + i) : (64 + tm * 4 + (i - 4)));
            atomicMin(&best[gr], bp);
        }
    }
}

// ---------------------------------------------------------------------------
// Kernel 3: gather q = cb[id], write quantized + ids(float), accumulate loss.
// ---------------------------------------------------------------------------
__global__ __launch_bounds__(256) void finalize(const float* __restrict__ x,
                                                const float* __restrict__ cb,
                                                const unsigned long long* __restrict__ best,
                                                float* __restrict__ out,
                                                float* __restrict__ loss_acc) {
    const int r = blockIdx.x;
    const int d = threadIdx.x;
    const int id = (int)(best[r] & 0xFFFFFFFFu);
    const float q  = cb[(size_t)id * DIM + d];
    const float xv = x[(size_t)r * DIM + d];
    out[(size_t)r * DIM + d] = q;
    float df = xv - q;
    float v = df * df;
    #pragma unroll
    for (int o = 32; o > 0; o >>= 1) v += __shfl_down(v, o, 64);
    __shared__ float w4[4];
    if ((d & 63) == 0) w4[d >> 6] = v;
    __syncthreads();
    if (d == 0) {
        atomicAdd(loss_acc, w4[0] + w4[1] + w4[2] + w4[3]);
        out[(size_t)N_TOK * DIM + r] = (float)id;
    }
}

__global__ void write_loss(const float* __restrict__ loss_acc, float* __restrict__ out) {
    out[(size_t)N_TOK * DIM + N_TOK] =
        loss_acc[0] * (1.25f / ((float)N_TOK * (float)DIM));
}

// ---------------------------------------------------------------------------
extern "C" void kernel_launch(void* const* d_in, const int* in_sizes, int n_in,
                              void* d_out, int out_size, void* d_ws, size_t ws_size,
                              hipStream_t stream) {
    const float* x     = (const float*)d_in[0];
    const float* emb   = (const float*)d_in[1];
    const float* w_out = (const float*)d_in[2];
    float* out = (float*)d_out;

    char* ws = (char*)d_ws;
    unsigned long long* best = (unsigned long long*)ws;          // 262144 B
    float* loss_acc = (float*)(ws + 262144);                     // -> 262400
    float* x2 = (float*)(ws + 262400);                           // -> 393472
    float* wT = (float*)(ws + 393472);                           // -> 655616
    float* cb = (float*)(ws + 655616);                           // -> 9044224
    float* c2 = (float*)(ws + 9044224);                          // -> 9076992

    hipMemsetAsync(best, 0xFF, 262144, stream);
    hipMemsetAsync(loss_acc, 0, 4, stream);

    transpose_w   <<<64,  256, 0, stream>>>(w_out, wT);
    build_codebook<<<KCB / KPB, 256, 0, stream>>>(emb, wT, cb);
    sumsq_np      <<<N_TOK * 2 / 256, 256, 0, stream>>>(x, x2);
    sumsq_np      <<<KCB * 2 / 256, 256, 0, stream>>>(cb, c2);
    score_argmin  <<<dim3(N_TOK / 128, KCB / 128), 256, 0, stream>>>(x, cb, c2, x2, best);
    finalize      <<<N_TOK, 256, 0, stream>>>(x, cb, best, out, loss_acc);
    write_loss    <<<1, 1, 0, stream>>>(loss_acc, out);
}